// Round 5
// baseline (158.244 us; speedup 1.0000x reference)
//
#include <hip/hip_runtime.h>
#include <hip/hip_bf16.h>

#define N_NODES 50000
#define N_EDGES 800000
#define D 128

#define RCAP  64         // slots per node; lambda=16, +12 sigma -> P(overflow)~1e-17
#define NBUCK 3125       // gather bucket = 16 nodes; 50000 = 3125*16 exactly

#define CONV_BLOCKS (N_EDGES / 256)   // 3125; exactly 1 edge per thread

using bf16x8 = __attribute__((ext_vector_type(8))) short;   // 8 bf16 (4 VGPRs)
using u16x8  = __attribute__((ext_vector_type(8))) unsigned short;
using f32x4  = __attribute__((ext_vector_type(4))) float;   // MFMA C/D

static __device__ __forceinline__ ushort f2bf(float f) {
    __hip_bfloat16 h = __float2bfloat16(f);   // RNE
    return *reinterpret_cast<ushort*>(&h);
}
static __device__ __forceinline__ float bf2f(ushort u) {
    return __uint_as_float(((unsigned)u) << 16);
}

// ---------------------------------------------------------------------------
// ws layout (~28.9 MB):
//   bcnt[N_NODES*16] int  (3.2 MB)  per-NODE counters, one per 64B line
//   pairs[N_NODES*64] int (12.8 MB) per-node padded windows: edges dst-sorted
//                                   BY CONSTRUCTION -> no CSR build needed
//   xb (bf16 x, 12.8 MB), wb (bf16 W chunk-major, 32 KB)
// Round-4 lesson: scatter cost is atomic ISSUE concentration, not just line
// contention -> 1 edge/thread spread over ALL blocks, counter = own line.
// ---------------------------------------------------------------------------

// Fused, sync-free: edge scatter (per-node atomics) + W->bf16 + x->bf16.
// Grid 3125 x 256 = exactly one edge per thread; conversion j = gt, gt+800000.
__global__ void __launch_bounds__(256)
convert_scatter(const float4* __restrict__ x4, ushort* __restrict__ xb,
                const float* __restrict__ W, ushort* __restrict__ wb,
                const int* __restrict__ src, const int* __restrict__ dst,
                int* __restrict__ bcnt, int* __restrict__ pairs) {
    const int gt = blockIdx.x * 256 + threadIdx.x;   // < 800000 always

    // edge: load + atomic slot claim issued FIRST (latency overlapped below)
    const int sv = src[gt];
    const int dv = dst[gt];
    const int pos = atomicAdd(&bcnt[dv * 16], 1);    // own 64B line per node

    // W -> bf16 chunk-major [k/8][o][8] (first 2048 threads)
    if (gt < 2048) {
        int o  = gt & 127;
        int kc = gt >> 7;
        const float4* wp = (const float4*)(W + (size_t)o * D + kc * 8);
        float4 w0 = wp[0], w1 = wp[1];
        bf16x8 hv;
        hv[0] = (short)f2bf(w0.x); hv[1] = (short)f2bf(w0.y);
        hv[2] = (short)f2bf(w0.z); hv[3] = (short)f2bf(w0.w);
        hv[4] = (short)f2bf(w1.x); hv[5] = (short)f2bf(w1.y);
        hv[6] = (short)f2bf(w1.z); hv[7] = (short)f2bf(w1.w);
        *(bf16x8*)&wb[gt * 8] = hv;
    }

    // streaming conversion: 1.6M float4, exactly 2 iterations/thread
#pragma unroll
    for (int k = 0; k < 2; ++k) {
        int j = gt + k * N_EDGES;          // N_EDGES == total4/2 == 800000
        float4 v = x4[j];
        ushort4 u = make_ushort4(f2bf(v.x), f2bf(v.y), f2bf(v.z), f2bf(v.w));
        *(ushort4*)(xb + (size_t)j * 4) = u;
    }

    // dependent store LAST: atomic round-trip hidden behind conversion
    if (pos < RCAP)                        // 12-sigma guard, never trips
        pairs[(dv << 6) + pos] = sv;
}

// ---------------------------------------------------------------------------
// Fused per-bucket kernel: padded-window edge lists (already dst-sorted) ->
// gather with two-node interleave -> MFMA GEMM + relu + residual.
// One block per 16-node bucket, 256 threads (4 waves). LDS 8448 B (Ew
// aliased over lsrc/aggL after an extra barrier). B-fragments from global
// wb (32 KB, L1-resident).
//   phase 1: lsrc [1024] ushort [0,2048) | aggL [16][136] bf16 [2048,6400)
//            lcnt [16] int [6400,6464)
//   phase 2: Ew [16][132] float [0,8448)
// ---------------------------------------------------------------------------
__global__ void __launch_bounds__(256)
csr_gather_gemm(const int* __restrict__ pairs, const int* __restrict__ bcnt,
                const ushort* __restrict__ xb, const ushort* __restrict__ wb,
                float* __restrict__ out) {
    __shared__ __align__(16) char lds[8448];
    ushort* lsrc = (ushort*)lds;                     // [1024]
    ushort* aggL = (ushort*)(lds + 2048);            // [16][136]
    int*    lcnt = (int*)(lds + 6400);               // [16]
    float*  Ew   = (float*)lds;                      // aliased, phase 2

    const int b    = blockIdx.x;
    const int tid  = threadIdx.x;
    const int lane = tid & 63;
    const int wv   = tid >> 6;
    const int m16  = lane & 15;
    const int q    = lane >> 4;

    // ---- per-node counts + coalesced window copy (no CSR build!) ----
    if (tid < 16) {
        int c = bcnt[(b * 16 + tid) * 16];
        lcnt[tid] = (c > RCAP) ? RCAP : c;
    }
#pragma unroll
    for (int k = 0; k < 4; ++k) {
        int i = tid + k * 256;             // 0..1023 = 16 nodes x 64 slots
        lsrc[i] = (ushort)(pairs[b * 1024 + i] & 0xFFFF);   // src < 50000 fits
    }
    __syncthreads();

    // ---- gather: wave wv owns nodes wv*4..wv*4+3; two-node interleave ----
    // Quarter-wave rows: 16 lanes x u16x8 (16B) = one 256B bf16 row per load;
    // dual-node 8-row step = 4 outstanding loads.
    const int c8 = m16 << 3;               // bf16 col 0,8,..,120
    const ushort* xbb = xb + c8;

    auto drain = [&](int t, int e, float* acc) {
        for (; t + 8 <= e; t += 8) {
            int s0 = lsrc[t + q];
            int s1v = lsrc[t + 4 + q];
            u16x8 u0 = *(const u16x8*)(xbb + (size_t)s0 * D);
            u16x8 u1 = *(const u16x8*)(xbb + (size_t)s1v * D);
#pragma unroll
            for (int j = 0; j < 8; ++j) acc[j] += bf2f(u0[j]) + bf2f(u1[j]);
        }
        for (; t + 4 <= e; t += 4) {
            int s = lsrc[t + q];
            u16x8 u = *(const u16x8*)(xbb + (size_t)s * D);
#pragma unroll
            for (int j = 0; j < 8; ++j) acc[j] += bf2f(u[j]);
        }
        const int rem = e - t;
        if (rem && q < rem) {
            int s = lsrc[t + q];
            u16x8 u = *(const u16x8*)(xbb + (size_t)s * D);
#pragma unroll
            for (int j = 0; j < 8; ++j) acc[j] += bf2f(u[j]);
        }
    };
    auto red_store = [&](int nloc, float* acc) {
#pragma unroll
        for (int j = 0; j < 8; ++j) {
            acc[j] += __shfl_xor(acc[j], 16, 64);
            acc[j] += __shfl_xor(acc[j], 32, 64);
        }
        if (q == 0) {                      // row write: 16 lanes x 16B, 256B
            u16x8 u;
#pragma unroll
            for (int j = 0; j < 8; ++j) u[j] = f2bf(acc[j]);
            *(u16x8*)&aggL[(size_t)nloc * 136 + c8] = u;
        }
    };

#pragma unroll 1
    for (int pm = 0; pm < 2; ++pm) {
        const int nA = wv * 4 + pm * 2;
        const int nB = nA + 1;
        int tA = nA << 6; const int eA = tA + lcnt[nA];
        int tB = nB << 6; const int eB = tB + lcnt[nB];
        float accA[8], accB[8];
#pragma unroll
        for (int j = 0; j < 8; ++j) { accA[j] = 0.f; accB[j] = 0.f; }

        // dual 8-row steps: 4 outstanding loads (wave-uniform control flow)
        while (tA + 8 <= eA && tB + 8 <= eB) {
            int a0 = lsrc[tA + q], a1 = lsrc[tA + 4 + q];
            int b0 = lsrc[tB + q], b1 = lsrc[tB + 4 + q];
            u16x8 uA0 = *(const u16x8*)(xbb + (size_t)a0 * D);
            u16x8 uA1 = *(const u16x8*)(xbb + (size_t)a1 * D);
            u16x8 uB0 = *(const u16x8*)(xbb + (size_t)b0 * D);
            u16x8 uB1 = *(const u16x8*)(xbb + (size_t)b1 * D);
#pragma unroll
            for (int j = 0; j < 8; ++j) {
                accA[j] += bf2f(uA0[j]) + bf2f(uA1[j]);
                accB[j] += bf2f(uB0[j]) + bf2f(uB1[j]);
            }
            tA += 8; tB += 8;
        }
        // dual 4-row steps: 2 outstanding
        while (tA + 4 <= eA && tB + 4 <= eB) {
            int a0 = lsrc[tA + q], b0 = lsrc[tB + q];
            u16x8 uA = *(const u16x8*)(xbb + (size_t)a0 * D);
            u16x8 uB = *(const u16x8*)(xbb + (size_t)b0 * D);
#pragma unroll
            for (int j = 0; j < 8; ++j) {
                accA[j] += bf2f(uA[j]);
                accB[j] += bf2f(uB[j]);
            }
            tA += 4; tB += 4;
        }
        drain(tA, eA, accA);
        drain(tB, eB, accB);
        red_store(nA, accA);
        red_store(nB, accB);
    }
    __syncthreads();                       // aggL complete

    // ---- MFMA GEMM: out[n][o] = relu(sum_k agg[n][k]*W[o][k]) + x[n][o] ----
    // All waves share the same 16 A-rows; wave wv computes cols wv*32..wv*32+31.
    bf16x8 a[4];
#pragma unroll
    for (int kb = 0; kb < 4; ++kb)
        a[kb] = *(const bf16x8*)&aggL[(size_t)m16 * 136 + kb * 32 + q * 8];
    __syncthreads();                       // all A-frag reads done: Ew may alias

    f32x4 acc[2];
#pragma unroll
    for (int tt = 0; tt < 2; ++tt) {
        const int t = wv * 2 + tt;
        acc[tt] = (f32x4){0.f, 0.f, 0.f, 0.f};
#pragma unroll
        for (int kb = 0; kb < 4; ++kb) {
            bf16x8 bfr = *(const bf16x8*)&wb[(((kb * 4 + q) * 128) + t * 16 + m16) * 8];
            acc[tt] = __builtin_amdgcn_mfma_f32_16x16x32_bf16(a[kb], bfr, acc[tt], 0, 0, 0);
        }
    }

#pragma unroll
    for (int tt = 0; tt < 2; ++tt) {
        const int t = wv * 2 + tt;
#pragma unroll
        for (int r = 0; r < 4; ++r)
            Ew[(q * 4 + r) * 132 + t * 16 + m16] = acc[tt][r];
    }
    __syncthreads();                       // Ew complete (cross-wave cols)

    // ---- epilogue: relu + residual, 2 float4 per thread, coalesced ----
#pragma unroll
    for (int k = 0; k < 2; ++k) {
        int idx = tid + k * 256;
        int row = idx >> 5;                // 0..15
        int c4  = (idx & 31) << 2;         // f32 col 0,4,..,124
        int node = b * 16 + row;           // < 50000 always (3125*16 exact)
        float4 v  = *(const float4*)&Ew[row * 132 + c4];
        ushort4 xu = *(const ushort4*)(xb + (size_t)node * D + c4);
        float4 o;
        o.x = fmaxf(v.x, 0.f) + bf2f(xu.x);
        o.y = fmaxf(v.y, 0.f) + bf2f(xu.y);
        o.z = fmaxf(v.z, 0.f) + bf2f(xu.z);
        o.w = fmaxf(v.w, 0.f) + bf2f(xu.w);
        *(float4*)(out + (size_t)node * D + c4) = o;
    }
}

// ===================== minimal fallback (tiny ws; never expected) ==========
__global__ void zero_out(float4* __restrict__ p, int n4) {
    int i = blockIdx.x * 256 + threadIdx.x;
    if (i < n4) p[i] = make_float4(0.f, 0.f, 0.f, 0.f);
}
__global__ void scatter_edges(const float* __restrict__ x,
                              const int* __restrict__ src,
                              const int* __restrict__ dst,
                              float* __restrict__ agg) {
    long long tid = (long long)blockIdx.x * 256 + threadIdx.x;
    if (tid >= (long long)N_EDGES * 32) return;
    int edge = (int)(tid >> 5);
    int c    = ((int)tid & 31) << 2;
    const float4 v = *(const float4*)(x + (size_t)src[edge] * D + c);
    float* p = agg + (size_t)dst[edge] * D + c;
    unsafeAtomicAdd(p + 0, v.x);
    unsafeAtomicAdd(p + 1, v.y);
    unsafeAtomicAdd(p + 2, v.z);
    unsafeAtomicAdd(p + 3, v.w);
}
__global__ void __launch_bounds__(256)
gemm_relu_res_f32(float* data, const float* __restrict__ W,
                  const float* __restrict__ x) {
    __shared__ __align__(16) char lds[50176];
    ushort* Wl = (ushort*)lds;
    ushort* Al = (ushort*)(lds + 32768);
    const int tid  = threadIdx.x;
    const int lane = tid & 63;
    const int wv   = tid >> 6;
    const int m16  = lane & 15;
    const int q    = lane >> 4;
#pragma unroll
    for (int i = 0; i < 8; ++i) {
        int g  = tid + i * 256;
        int o  = g & 127;
        int kc = g >> 7;
        const float4* wp = (const float4*)(W + (size_t)o * D + kc * 8);
        float4 w0 = wp[0], w1 = wp[1];
        bf16x8 hv;
        hv[0] = (short)f2bf(w0.x); hv[1] = (short)f2bf(w0.y);
        hv[2] = (short)f2bf(w0.z); hv[3] = (short)f2bf(w0.w);
        hv[4] = (short)f2bf(w1.x); hv[5] = (short)f2bf(w1.y);
        hv[6] = (short)f2bf(w1.z); hv[7] = (short)f2bf(w1.w);
        *(bf16x8*)&Wl[g * 8] = hv;
    }
    __syncthreads();
    const int nb = blockIdx.x * 64 + wv * 16;
    ushort* Aw = &Al[wv * (16 * 136)];
#pragma unroll
    for (int m = 0; m < 16; ++m) {
        int node = nb + m;
        float2 v = make_float2(0.f, 0.f);
        if (node < N_NODES)
            v = *(const float2*)(data + (size_t)node * D + lane * 2);
        *(ushort2*)&Aw[m * 136 + lane * 2] = make_ushort2(f2bf(v.x), f2bf(v.y));
    }
    bf16x8 a[4];
#pragma unroll
    for (int kb = 0; kb < 4; ++kb)
        a[kb] = *(const bf16x8*)&Aw[m16 * 136 + kb * 32 + q * 8];
    f32x4 acc[8];
#pragma unroll
    for (int t = 0; t < 8; ++t) {
        acc[t] = (f32x4){0.f, 0.f, 0.f, 0.f};
#pragma unroll
        for (int kb = 0; kb < 4; ++kb) {
            bf16x8 bfr = *(const bf16x8*)&Wl[(((kb * 4 + q) * 128) + t * 16 + m16) * 8];
            acc[t] = __builtin_amdgcn_mfma_f32_16x16x32_bf16(a[kb], bfr, acc[t], 0, 0, 0);
        }
    }
    __syncthreads();
    float* Ew = (float*)(lds + wv * 8448);
#pragma unroll
    for (int t = 0; t < 8; ++t)
#pragma unroll
        for (int r = 0; r < 4; ++r)
            Ew[(q * 4 + r) * 132 + t * 16 + m16] = acc[t][r];
    const int h  = lane >> 5;
    const int c4 = (lane & 31) << 2;
#pragma unroll
    for (int j = 0; j < 8; ++j) {
        int r = j * 2 + h;
        int node = nb + r;
        if (node < N_NODES) {
            float4 v  = *(const float4*)&Ew[r * 132 + c4];
            float4 xi = *(const float4*)(x + (size_t)node * D + c4);
            float4 o;
            o.x = fmaxf(v.x, 0.f) + xi.x;
            o.y = fmaxf(v.y, 0.f) + xi.y;
            o.z = fmaxf(v.z, 0.f) + xi.z;
            o.w = fmaxf(v.w, 0.f) + xi.w;
            *(float4*)(data + (size_t)node * D + c4) = o;
        }
    }
}

extern "C" void kernel_launch(void* const* d_in, const int* in_sizes, int n_in,
                              void* d_out, int out_size, void* d_ws, size_t ws_size,
                              hipStream_t stream) {
    const float* x   = (const float*)d_in[0];
    const int*   src = (const int*)d_in[1];   // harness passes integers as int32
    const int*   dst = (const int*)d_in[2];
    const float* W   = (const float*)d_in[3];
    float* out = (float*)d_out;

    char* ws = (char*)d_ws;
    int*    bcnt  = (int*)ws;        ws += (size_t)N_NODES * 64;        // 3.2 MB
    int*    pairs = (int*)ws;        ws += (size_t)N_NODES * RCAP * 4;  // 12.8 MB
    ushort* xb    = (ushort*)ws;     ws += (size_t)N_NODES * D * 2;     // 12.8 MB
    ushort* wb    = (ushort*)ws;     ws += (size_t)D * D * 2;           // 32 KB
    const bool big_ws = (ws_size >= (size_t)(ws - (char*)d_ws));

    if (big_ws) {
        hipMemsetAsync(bcnt, 0, (size_t)N_NODES * 64, stream);   // 3.2 MB fill
        convert_scatter<<<CONV_BLOCKS, 256, 0, stream>>>(
            (const float4*)x, xb, W, wb, src, dst, bcnt, pairs);
        csr_gather_gemm<<<NBUCK, 256, 0, stream>>>(pairs, bcnt, xb, wb, out);
    } else {
        // slow-but-correct fallback (no scratch needed beyond d_out)
        int n4 = N_NODES * D / 4;
        zero_out<<<(n4 + 255) / 256, 256, 0, stream>>>((float4*)out, n4);
        long long n_scatter = (long long)N_EDGES * 32;
        scatter_edges<<<(int)((n_scatter + 255) / 256), 256, 0, stream>>>(
            x, src, dst, out);
        gemm_relu_res_f32<<<(N_NODES + 63) / 64, 256, 0, stream>>>(out, W, x);
    }
}